// Round 11
// baseline (1919.192 us; speedup 1.0000x reference)
//
#include <hip/hip_runtime.h>
#include <hip/hip_fp16.h>
#include <hip/hip_cooperative_groups.h>

#define NN 50000
#define EE 800000
#define FIN 128
#define HH 64
#define TT 8
#define GG 64
#define NCONVS 3
#define BN_EPS 1e-5f
#define RNODES 64             // nodes per readout tile
#define NBKT 196              // ceil(NN/256) buckets of 256 nodes
#define NBLK 782              // (NN+63)/64 mm tiles (64 rows each)
#define NRD 782               // readout tiles
#define NGQ 784               // NBKT*4 gather quarter-bucket chunks
#define NSCC 391              // bscatter chunks (2048 edges each)
#define NBCC 391              // bcount chunks (2048 edges each)
#define SMEMSZ 27648          // max over phases (mm FIN)

namespace cg = cooperative_groups;

typedef _Float16 h2f __attribute__((ext_vector_type(2)));

struct GinParams {
  const float* x; const int* ei; const int* batch;
  const float *fh_W1, *fh_b1, *fh_g1, *fh_be1, *fh_W2, *fh_b2, *fh_g2, *fh_be2;
  const float *cv_W1, *cv_b1, *cv_g1, *cv_be1, *cv_W2, *cv_b2, *cv_g2, *cv_be2;
  const float *lin_W, *lin_b;
  float* out; float* h;
  float* stats; unsigned* outmax;
  int *bcnt, *bbase, *bcur;
  unsigned long long* ebuf;
  __half *y1, *y2, *agg;
};

__device__ __forceinline__ unsigned enc_f32(float x) {
  unsigned u = __float_as_uint(x);
  return (u & 0x80000000u) ? ~u : (u | 0x80000000u);
}
__device__ __forceinline__ float dec_f32(unsigned e) {
  unsigned u = (e & 0x80000000u) ? (e & 0x7fffffffu) : ~e;
  return __uint_as_float(u);
}
__device__ __forceinline__ float fdot2f(int a, int b, float c) {
#if __has_builtin(__builtin_amdgcn_fdot2)
  return __builtin_amdgcn_fdot2(__builtin_bit_cast(h2f, a),
                                __builtin_bit_cast(h2f, b), c, false);
#else
  const __half2 ha = __builtin_bit_cast(__half2, a);
  const __half2 hb = __builtin_bit_cast(__half2, b);
  const float2 fa = __half22float2(ha), fb = __half22float2(hb);
  return fmaf(fa.y, fb.y, fmaf(fa.x, fb.x, c));
#endif
}
__device__ __forceinline__ void bn_ssl(float* ssl, const float* stats_in,
                                       const float* gamma, const float* beta) {
  const int t = threadIdx.x;
  if (t < 64) {
    const float inv = 1.f / (float)NN;
    const float mean = stats_in[t] * inv;
    const float var = stats_in[64 + t] * inv - mean * mean;
    const float sc = gamma[t] * rsqrtf(var + BN_EPS);
    ssl[t] = sc;
    ssl[64 + t] = fmaf(-mean, sc, beta[t]);
  }
}

// -------- mm body: 256 threads, 64-row tile, thread = 2 rows x 8 cols --------
// MODE 0: fp32 in (K=FIN); MODE 1: relu(BN(hin)); MODE 2: relu(BN(hin))+agg
template <int K, int MODE>
__device__ __forceinline__ void mm_body(
    char* smemc, int tile, const float* __restrict__ in,
    const __half* __restrict__ hin, const __half* __restrict__ agg,
    const float* __restrict__ stats_in, const float* __restrict__ gamma,
    const float* __restrict__ beta, const float* __restrict__ W,
    const float* __restrict__ bias, __half* __restrict__ y16,
    float* __restrict__ stats_out) {
  constexpr int NPH = K / 64;
  __half2* Wl2 = (__half2*)smemc;                          // (K/2)*64
  __half2* AT2 = (__half2*)(smemc + (size_t)K * 128);      // 32*68
  float* ssl = (float*)(smemc + (size_t)K * 128 + 32 * 68 * 4);  // 128
  float* sred = ssl + 128;                                 // 4*128
  const int t = threadIdx.x;
  if (MODE != 0) {
    bn_ssl(ssl, stats_in, gamma, beta);
    __syncthreads();
  }
#pragma unroll
  for (int i = 0; i < K / 8; ++i) {
    const int idx = t + i * 256;
    const int kk = idx >> 6, c = idx & 63;
    Wl2[idx] = __floats2half2_rn(W[(2 * kk) * HH + c], W[(2 * kk + 1) * HH + c]);
  }
  const int srow = t >> 2, sq = t & 3;
  const int grow_s = tile * 64 + srow;
  const int cg = t & 7, rg = t >> 3;
  const int c0 = cg * 8, r0 = rg * 2;
  float acc[2][8] = {};
#pragma unroll
  for (int p = 0; p < NPH; ++p) {
    if (p > 0) __syncthreads();
    if (grow_s < NN) {
      if (MODE == 0) {
#pragma unroll
        for (int q = 0; q < 4; ++q) {
          const int cc = p * 64 + sq * 16 + q * 4;
          const float4 v = *(const float4*)&in[(size_t)grow_s * K + cc];
          const int kk = sq * 8 + q * 2;
          AT2[(kk + 0) * 68 + srow] = __floats2half2_rn(v.x, v.y);
          AT2[(kk + 1) * 68 + srow] = __floats2half2_rn(v.z, v.w);
        }
      } else {
#pragma unroll
        for (int q = 0; q < 2; ++q) {
          const int cc = sq * 16 + q * 8;
          const int4 rv = *(const int4*)&hin[(size_t)grow_s * HH + cc];
          const __half2* hp = (const __half2*)&rv;
          float f[8];
          {
            const float2 f0 = __half22float2(hp[0]);
            const float2 f1 = __half22float2(hp[1]);
            const float2 f2 = __half22float2(hp[2]);
            const float2 f3 = __half22float2(hp[3]);
            f[0] = f0.x; f[1] = f0.y; f[2] = f1.x; f[3] = f1.y;
            f[4] = f2.x; f[5] = f2.y; f[6] = f3.x; f[7] = f3.y;
          }
#pragma unroll
          for (int j = 0; j < 8; ++j)
            f[j] = fmaxf(fmaf(f[j], ssl[cc + j], ssl[64 + cc + j]), 0.f);
          if (MODE == 2) {
            const int4 av = *(const int4*)&agg[(size_t)grow_s * HH + cc];
            const __half2* ap = (const __half2*)&av;
            const float2 a0 = __half22float2(ap[0]);
            const float2 a1 = __half22float2(ap[1]);
            const float2 a2 = __half22float2(ap[2]);
            const float2 a3 = __half22float2(ap[3]);
            f[0] += a0.x; f[1] += a0.y; f[2] += a1.x; f[3] += a1.y;
            f[4] += a2.x; f[5] += a2.y; f[6] += a3.x; f[7] += a3.y;
          }
          const int kk = sq * 8 + q * 4;
          AT2[(kk + 0) * 68 + srow] = __floats2half2_rn(f[0], f[1]);
          AT2[(kk + 1) * 68 + srow] = __floats2half2_rn(f[2], f[3]);
          AT2[(kk + 2) * 68 + srow] = __floats2half2_rn(f[4], f[5]);
          AT2[(kk + 3) * 68 + srow] = __floats2half2_rn(f[6], f[7]);
        }
      }
    } else {
      const __half2 z = __floats2half2_rn(0.f, 0.f);
#pragma unroll
      for (int j = 0; j < 8; ++j) AT2[(sq * 8 + j) * 68 + srow] = z;
    }
    __syncthreads();
#pragma unroll 4
    for (int kk = 0; kk < 32; ++kk) {
      const int4 w0 = *(const int4*)&Wl2[(p * 32 + kk) * HH + c0];
      const int4 w1 = *(const int4*)&Wl2[(p * 32 + kk) * HH + c0 + 4];
      const int2 av = *(const int2*)&AT2[kk * 68 + r0];
      const int wu[8] = {w0.x, w0.y, w0.z, w0.w, w1.x, w1.y, w1.z, w1.w};
      const int au[2] = {av.x, av.y};
#pragma unroll
      for (int r = 0; r < 2; ++r)
#pragma unroll
        for (int c = 0; c < 8; ++c)
          acc[r][c] = fdot2f(au[r], wu[c], acc[r][c]);
    }
  }
  const float4 bb0 = *(const float4*)&bias[c0];
  const float4 bb1 = *(const float4*)&bias[c0 + 4];
  const float bbv[8] = {bb0.x, bb0.y, bb0.z, bb0.w, bb1.x, bb1.y, bb1.z, bb1.w};
  float st_s[8] = {}, st_q[8] = {};
  const int row0 = tile * 64 + r0;
#pragma unroll
  for (int ri = 0; ri < 2; ++ri) {
    const int grow = row0 + ri;
    if (grow < NN) {
      float o[8];
#pragma unroll
      for (int c = 0; c < 8; ++c) {
        o[c] = acc[ri][c] + bbv[c];
        st_s[c] += o[c];
        st_q[c] = fmaf(o[c], o[c], st_q[c]);
      }
      const __half2 p0 = __floats2half2_rn(o[0], o[1]);
      const __half2 p1 = __floats2half2_rn(o[2], o[3]);
      const __half2 p2 = __floats2half2_rn(o[4], o[5]);
      const __half2 p3 = __floats2half2_rn(o[6], o[7]);
      int4 pk;
      pk.x = *(const int*)&p0; pk.y = *(const int*)&p1;
      pk.z = *(const int*)&p2; pk.w = *(const int*)&p3;
      *(int4*)&y16[(size_t)grow * HH + c0] = pk;
    }
  }
#pragma unroll
  for (int off = 8; off <= 32; off <<= 1) {
#pragma unroll
    for (int c = 0; c < 8; ++c) {
      st_s[c] += __shfl_xor(st_s[c], off);
      st_q[c] += __shfl_xor(st_q[c], off);
    }
  }
  const int wave = t >> 6, lane = t & 63;
  if (lane < 8) {
#pragma unroll
    for (int c = 0; c < 8; ++c) {
      sred[wave * 128 + lane * 8 + c] = st_s[c];
      sred[wave * 128 + 64 + lane * 8 + c] = st_q[c];
    }
  }
  __syncthreads();
  if (t < 128)
    atomicAdd(&stats_out[t],
              sred[t] + sred[128 + t] + sred[256 + t] + sred[384 + t]);
}

// -------- bcount: 2048-edge chunk, LDS histogram --------
__device__ __forceinline__ void bcount_body(char* smemc, int chunk,
                                            const int* __restrict__ ei,
                                            int* __restrict__ bcnt) {
  int* hist = (int*)smemc;
  const int t = threadIdx.x;
  hist[t] = 0;
  __syncthreads();
#pragma unroll
  for (int i = 0; i < 8; ++i) {
    const int e = chunk * 2048 + i * 256 + t;
    if (e < EE) atomicAdd(&hist[ei[EE + e] >> 8], 1);
  }
  __syncthreads();
  if (t < NBKT && hist[t]) atomicAdd(&bcnt[t], hist[t]);
}

// -------- bscan: single block --------
__device__ __forceinline__ void bscan_body(char* smemc,
                                           const int* __restrict__ bcnt,
                                           int* __restrict__ bbase,
                                           int* __restrict__ bcur) {
  int* s = (int*)smemc;
  const int t = threadIdx.x;
  const int v = (t < NBKT) ? bcnt[t] : 0;
  s[t] = v;
  __syncthreads();
  for (int off = 1; off < 256; off <<= 1) {
    const int u = (t >= off) ? s[t - off] : 0;
    __syncthreads();
    s[t] += u;
    __syncthreads();
  }
  const int excl = s[t] - v;
  if (t < NBKT) {
    bbase[t] = excl;
    bcur[t] = excl;
  }
  if (t == 0) bbase[NBKT] = EE;
}

// -------- bscatter: 2048-edge chunk --------
__device__ __forceinline__ void bscatter_body(
    char* smemc, int chunk, const int* __restrict__ ei, int* __restrict__ bcur,
    unsigned long long* __restrict__ ebuf) {
  int* lcnt = (int*)smemc;
  int* lbase = lcnt + 256;
  const int t = threadIdx.x;
  lcnt[t] = 0;
  __syncthreads();
  const int e0 = chunk * 2048;
  int mysrc[8], mydl[8], mybkt[8], myloc[8];
#pragma unroll
  for (int i = 0; i < 8; ++i) {
    const int e = e0 + i * 256 + t;
    if (e < EE) {
      const int dst = ei[EE + e];
      mybkt[i] = dst >> 8;
      mydl[i] = dst & 255;
      mysrc[i] = ei[e];
      myloc[i] = atomicAdd(&lcnt[mybkt[i]], 1);
    } else {
      mybkt[i] = -1;
    }
  }
  __syncthreads();
  if (lcnt[t]) lbase[t] = atomicAdd(&bcur[t], lcnt[t]);
  __syncthreads();
#pragma unroll
  for (int i = 0; i < 8; ++i) {
    if (mybkt[i] >= 0) {
      const int pos = lbase[mybkt[i]] + myloc[i];
      ebuf[pos] = ((unsigned long long)(unsigned)mydl[i] << 32) |
                  (unsigned)mysrc[i];
    }
  }
}

// -------- bgather: quarter-bucket (16 cols), edge-parallel, LDS fp32 acc -----
__device__ __forceinline__ void bgather_body(
    char* smemc, int chunk, const int* __restrict__ bbase,
    const unsigned long long* __restrict__ ebuf, const __half* __restrict__ y,
    const float* __restrict__ stats_in, const float* __restrict__ gamma,
    const float* __restrict__ beta, __half* __restrict__ agg) {
  float* accs = (float*)smemc;            // 256*16
  float* ssl = accs + 256 * 16;           // 128
  const int t = threadIdx.x;
  const int b = chunk >> 2, qu = chunk & 3;
  const int c0 = qu * 16;
  bn_ssl(ssl, stats_in, gamma, beta);
#pragma unroll
  for (int i = 0; i < 16; ++i) accs[t + i * 256] = 0.f;
  __syncthreads();
  const int e0 = bbase[b], e1 = bbase[b + 1];
  const int lh = t & 1;
  const int cc = c0 + lh * 8;
  float sc[8], sh[8];
#pragma unroll
  for (int j = 0; j < 8; ++j) {
    sc[j] = ssl[cc + j];
    sh[j] = ssl[64 + cc + j];
  }
  for (int j = e0 + (t >> 1); j < e1; j += 128) {
    const unsigned long long u = ebuf[j];
    const int src = (int)(u & 0xffffffffu);
    const int dl = (int)(u >> 32);
    const int4 rv = *(const int4*)&y[(size_t)src * HH + cc];
    const __half2* hp = (const __half2*)&rv;
    const float2 f0 = __half22float2(hp[0]);
    const float2 f1 = __half22float2(hp[1]);
    const float2 f2 = __half22float2(hp[2]);
    const float2 f3 = __half22float2(hp[3]);
    float* arow = &accs[dl * 16 + lh * 8];
    atomicAdd(&arow[0], fmaxf(fmaf(f0.x, sc[0], sh[0]), 0.f));
    atomicAdd(&arow[1], fmaxf(fmaf(f0.y, sc[1], sh[1]), 0.f));
    atomicAdd(&arow[2], fmaxf(fmaf(f1.x, sc[2], sh[2]), 0.f));
    atomicAdd(&arow[3], fmaxf(fmaf(f1.y, sc[3], sh[3]), 0.f));
    atomicAdd(&arow[4], fmaxf(fmaf(f2.x, sc[4], sh[4]), 0.f));
    atomicAdd(&arow[5], fmaxf(fmaf(f2.y, sc[5], sh[5]), 0.f));
    atomicAdd(&arow[6], fmaxf(fmaf(f3.x, sc[6], sh[6]), 0.f));
    atomicAdd(&arow[7], fmaxf(fmaf(f3.y, sc[7], sh[7]), 0.f));
  }
  __syncthreads();
  const int n = b * 256 + t;
  if (n < NN) {
    const float* a = &accs[t * 16];
    int4 pk0, pk1;
    __half2 h0 = __floats2half2_rn(a[0], a[1]);
    __half2 h1 = __floats2half2_rn(a[2], a[3]);
    __half2 h2 = __floats2half2_rn(a[4], a[5]);
    __half2 h3 = __floats2half2_rn(a[6], a[7]);
    pk0.x = *(const int*)&h0; pk0.y = *(const int*)&h1;
    pk0.z = *(const int*)&h2; pk0.w = *(const int*)&h3;
    h0 = __floats2half2_rn(a[8], a[9]);
    h1 = __floats2half2_rn(a[10], a[11]);
    h2 = __floats2half2_rn(a[12], a[13]);
    h3 = __floats2half2_rn(a[14], a[15]);
    pk1.x = *(const int*)&h0; pk1.y = *(const int*)&h1;
    pk1.z = *(const int*)&h2; pk1.w = *(const int*)&h3;
    *(int4*)&agg[(size_t)n * HH + c0] = pk0;
    *(int4*)&agg[(size_t)n * HH + c0 + 8] = pk1;
  }
}

// -------- readout: 64-node tile --------
template <int WMODE>
__device__ __forceinline__ void readout_body(
    char* smemc, int tile, const __half* __restrict__ y2,
    const float* __restrict__ stats_in, const float* __restrict__ gamma,
    const float* __restrict__ beta, float* __restrict__ hout,
    const float* __restrict__ linW, const float* __restrict__ linb,
    const int* __restrict__ batch, unsigned* __restrict__ outmax) {
  float* Wl = (float*)smemc;                 // 576
  float* lb = Wl + 576;                      // 8
  float* ssl = lb + 8;                       // 128
  unsigned* smax = (unsigned*)(ssl + 128);   // 64
  const int t = threadIdx.x;
  if (t < 64) {
#pragma unroll
    for (int j = 0; j < 8; ++j) Wl[t * 9 + j] = linW[t * 8 + j];
  }
  bn_ssl(ssl, stats_in, gamma, beta);
  if (t < 8) lb[t] = linb[t];
  if (t >= 64 && t < 128) smax[t - 64] = 0u;
  const int gfirst = batch[tile * RNODES < NN ? tile * RNODES : NN - 1];
  __syncthreads();
  const int nl = t >> 3;
  const int c0 = (t & 7) * 8;
  const int b0 = t & 1, b1 = (t >> 1) & 1, b2 = (t >> 2) & 1;
#pragma unroll
  for (int chunk = 0; chunk < RNODES / 32; ++chunk) {
    const int n = tile * RNODES + chunk * 32 + nl;
    if (n < NN) {
      float hv[8];
      {
        const int4 rv = *(const int4*)&y2[(size_t)n * HH + c0];
        const __half2* hp = (const __half2*)&rv;
        const float2 f0 = __half22float2(hp[0]);
        const float2 f1 = __half22float2(hp[1]);
        const float2 f2 = __half22float2(hp[2]);
        const float2 f3 = __half22float2(hp[3]);
        hv[0] = fmaxf(fmaf(f0.x, ssl[c0 + 0], ssl[64 + c0 + 0]), 0.f);
        hv[1] = fmaxf(fmaf(f0.y, ssl[c0 + 1], ssl[64 + c0 + 1]), 0.f);
        hv[2] = fmaxf(fmaf(f1.x, ssl[c0 + 2], ssl[64 + c0 + 2]), 0.f);
        hv[3] = fmaxf(fmaf(f1.y, ssl[c0 + 3], ssl[64 + c0 + 3]), 0.f);
        hv[4] = fmaxf(fmaf(f2.x, ssl[c0 + 4], ssl[64 + c0 + 4]), 0.f);
        hv[5] = fmaxf(fmaf(f2.y, ssl[c0 + 5], ssl[64 + c0 + 5]), 0.f);
        hv[6] = fmaxf(fmaf(f3.x, ssl[c0 + 6], ssl[64 + c0 + 6]), 0.f);
        hv[7] = fmaxf(fmaf(f3.y, ssl[c0 + 7], ssl[64 + c0 + 7]), 0.f);
      }
      if (WMODE == 1) {
        *(float4*)&hout[(size_t)n * HH + c0] =
            make_float4(hv[0], hv[1], hv[2], hv[3]);
        *(float4*)&hout[(size_t)n * HH + c0 + 4] =
            make_float4(hv[4], hv[5], hv[6], hv[7]);
      }
      float rr[8] = {0, 0, 0, 0, 0, 0, 0, 0};
#pragma unroll
      for (int j = 0; j < 8; ++j) {
        const float a = hv[j];
        const int k = c0 + j;
#pragma unroll
        for (int u = 0; u < 8; ++u) rr[u] = fmaf(a, Wl[k * 9 + u], rr[u]);
      }
      float s4[4];
#pragma unroll
      for (int i = 0; i < 4; ++i) {
        const float keepv = b0 ? rr[2 * i + 1] : rr[2 * i];
        const float send = b0 ? rr[2 * i] : rr[2 * i + 1];
        s4[i] = keepv + __shfl_xor(send, 1);
      }
      float s2[2];
#pragma unroll
      for (int i = 0; i < 2; ++i) {
        const float keepv = b1 ? s4[2 * i + 1] : s4[2 * i];
        const float send = b1 ? s4[2 * i] : s4[2 * i + 1];
        s2[i] = keepv + __shfl_xor(send, 2);
      }
      const float keepv = b2 ? s2[1] : s2[0];
      const float send = b2 ? s2[0] : s2[1];
      const float v = keepv + __shfl_xor(send, 4) + lb[t & 7];
      const int g = batch[n];
      const int gidx = g - gfirst;
      const unsigned ev = enc_f32(v);
      if (gidx < 8)
        atomicMax(&smax[gidx * 8 + (t & 7)], ev);
      else
        atomicMax(&outmax[g * 8 + (t & 7)], ev);
    }
  }
  __syncthreads();
  if (t < 64) {
    const unsigned vv = smax[t];
    if (vv) atomicMax(&outmax[(gfirst + (t >> 3)) * 8 + (t & 7)], vv);
  }
}

// ---------------- the cooperative mega-kernel ----------------
__global__ __launch_bounds__(256, 4) void gin_mega(GinParams p) {
  cg::grid_group grid = cg::this_grid();
  __shared__ alignas(16) char smem[SMEMSZ];
  const int bid = blockIdx.x, G = gridDim.x;
  const int t = threadIdx.x;

  // Phase A: zero stats(1024w) + outmax(2048w) + bcnt(256w), contiguous
  for (int i = bid * 256 + t; i < 1024 + 2048 + 256; i += G * 256)
    ((unsigned*)p.stats)[i] = 0u;
  grid.sync();

  // Phase B: first_h mm1 (FIN) || bucket count
  for (int i = bid; i < NBLK + NBCC; i += G) {
    __syncthreads();
    if (i < NBLK)
      mm_body<FIN, 0>(smem, i, p.x, nullptr, nullptr, nullptr, nullptr,
                      nullptr, p.fh_W1, p.fh_b1, p.y1, p.stats);
    else
      bcount_body(smem, i - NBLK, p.ei, p.bcnt);
  }
  grid.sync();

  // Phase C: bucket scan (block 0)
  if (bid == 0) bscan_body(smem, p.bcnt, p.bbase, p.bcur);
  grid.sync();

  // Phase D: first_h mm2 || bucket scatter
  for (int i = bid; i < NBLK + NSCC; i += G) {
    __syncthreads();
    if (i < NBLK)
      mm_body<HH, 1>(smem, i, nullptr, p.y1, nullptr, p.stats, p.fh_g1,
                     p.fh_be1, p.fh_W2, p.fh_b2, p.y2, p.stats + 128);
    else
      bscatter_body(smem, i - NBLK, p.ei, p.bcur, p.ebuf);
  }
  grid.sync();

  // Phase E: readout layer-0 || gather layer-0
  for (int i = bid; i < NRD + NGQ; i += G) {
    __syncthreads();
    if (i < NRD)
      readout_body<0>(smem, i, p.y2, p.stats + 128, p.fh_g2, p.fh_be2, p.h,
                      p.lin_W, p.lin_b, p.batch, p.outmax);
    else
      bgather_body(smem, i - NRD, p.bbase, p.ebuf, p.y2, p.stats + 128,
                   p.fh_g2, p.fh_be2, p.agg);
  }
  grid.sync();

  // GIN conv layers
  for (int l = 0; l < NCONVS; ++l) {
    const float* sprev = p.stats + (1 + 2 * l) * 128;
    float* sA = p.stats + (2 + 2 * l) * 128;
    float* sB = p.stats + (3 + 2 * l) * 128;
    const float* pg = (l == 0) ? p.fh_g2 : p.cv_g2 + (l - 1) * HH;
    const float* pb = (l == 0) ? p.fh_be2 : p.cv_be2 + (l - 1) * HH;
    for (int i = bid; i < NBLK; i += G) {
      __syncthreads();
      mm_body<HH, 2>(smem, i, nullptr, p.y2, p.agg, sprev, pg, pb,
                     p.cv_W1 + l * HH * HH, p.cv_b1 + l * HH, p.y1, sA);
    }
    grid.sync();
    for (int i = bid; i < NBLK; i += G) {
      __syncthreads();
      mm_body<HH, 1>(smem, i, nullptr, p.y1, nullptr, sA, p.cv_g1 + l * HH,
                     p.cv_be1 + l * HH, p.cv_W2 + l * HH * HH,
                     p.cv_b2 + l * HH, p.y2, sB);
    }
    grid.sync();
    if (l < NCONVS - 1) {
      for (int i = bid; i < NRD + NGQ; i += G) {
        __syncthreads();
        if (i < NRD)
          readout_body<0>(smem, i, p.y2, sB, p.cv_g2 + l * HH,
                          p.cv_be2 + l * HH, p.h, p.lin_W + (l + 1) * HH * TT,
                          p.lin_b + (l + 1) * TT, p.batch,
                          p.outmax + (l + 1) * GG * TT);
        else
          bgather_body(smem, i - NRD, p.bbase, p.ebuf, p.y2, sB,
                       p.cv_g2 + l * HH, p.cv_be2 + l * HH, p.agg);
      }
    } else {
      for (int i = bid; i < NRD; i += G) {
        __syncthreads();
        readout_body<1>(smem, i, p.y2, sB, p.cv_g2 + l * HH,
                        p.cv_be2 + l * HH, p.h, p.lin_W + (l + 1) * HH * TT,
                        p.lin_b + (l + 1) * TT, p.batch,
                        p.outmax + (l + 1) * GG * TT);
      }
    }
    grid.sync();
  }

  // Phase P: combine (block 0)
  if (bid == 0) {
    for (int i = t; i < GG * TT; i += 256) {
      float s = 0.f;
#pragma unroll
      for (int l = 0; l < 4; ++l) s += dec_f32(p.outmax[l * GG * TT + i]);
      p.out[i] = s;
    }
  }
}

extern "C" void kernel_launch(void* const* d_in, const int* in_sizes, int n_in,
                              void* d_out, int out_size, void* d_ws,
                              size_t ws_size, hipStream_t stream) {
  GinParams p;
  p.x      = (const float*)d_in[0];
  p.ei     = (const int*)d_in[1];
  p.batch  = (const int*)d_in[2];
  p.fh_W1  = (const float*)d_in[3];
  p.fh_b1  = (const float*)d_in[4];
  p.fh_g1  = (const float*)d_in[5];
  p.fh_be1 = (const float*)d_in[6];
  p.fh_W2  = (const float*)d_in[7];
  p.fh_b2  = (const float*)d_in[8];
  p.fh_g2  = (const float*)d_in[9];
  p.fh_be2 = (const float*)d_in[10];
  p.cv_W1  = (const float*)d_in[11];
  p.cv_b1  = (const float*)d_in[12];
  p.cv_g1  = (const float*)d_in[13];
  p.cv_be1 = (const float*)d_in[14];
  p.cv_W2  = (const float*)d_in[15];
  p.cv_b2  = (const float*)d_in[16];
  p.cv_g2  = (const float*)d_in[17];
  p.cv_be2 = (const float*)d_in[18];
  p.lin_W  = (const float*)d_in[19];
  p.lin_b  = (const float*)d_in[20];

  p.out = (float*)d_out;
  p.h = p.out + GG * TT;

  char* w = (char*)d_ws;
  p.stats = (float*)w;                    w += 8 * 128 * 4;       // 1024 w
  p.outmax = (unsigned*)w;                w += 4 * GG * TT * 4;   // 2048 w
  p.bcnt = (int*)w;                       w += 256 * 4;           // 256 w
  p.bbase = (int*)w;                      w += 256 * 4;
  p.bcur = (int*)w;                       w += 256 * 4;
  w = (char*)(((size_t)w + 15) & ~(size_t)15);
  p.ebuf = (unsigned long long*)w;        w += (size_t)EE * 8;
  p.y1 = (__half*)w;                      w += (size_t)NN * HH * 2;
  p.y2 = (__half*)w;                      w += (size_t)NN * HH * 2;
  p.agg = (__half*)w;                     w += (size_t)NN * HH * 2;

  int nb = 2;
  if (hipOccupancyMaxActiveBlocksPerMultiprocessor(
          &nb, (const void*)gin_mega, 256, 0) != hipSuccess || nb < 1)
    nb = 2;
  int gridsz = nb * 256;
  if (gridsz > 1024) gridsz = 1024;

  void* args[] = {(void*)&p};
  hipLaunchCooperativeKernel((const void*)gin_mega, dim3(gridsz), dim3(256),
                             args, 0, stream);
}

// Round 12
// 329.715 us; speedup vs baseline: 5.8208x; 5.8208x over previous
//
#include <hip/hip_runtime.h>
#include <hip/hip_fp16.h>

#define NN 50000
#define EE 800000
#define FIN 128
#define HH 64
#define TT 8
#define GG 64
#define NCONVS 3
#define BN_EPS 1e-5f
#define RNODES 64             // nodes per readout block
#define NBKT 196              // ceil(NN/256) buckets of 256 nodes
#define SCAT_CHUNK 1024       // edges per bscatter block (128 thr x 8)
#define NBLK 782              // (NN+63)/64   mm blocks (128 threads)
#define NRD 782               // readout blocks
#define NGA 1563              // (NN*8+255)/256 gather blocks
#define NSC 782               // ceil(EE/SCAT_CHUNK)
#define NB_BC 256             // bcount blocks (128 threads)

typedef _Float16 h2f __attribute__((ext_vector_type(2)));

__device__ __forceinline__ unsigned enc_f32(float x) {
  unsigned u = __float_as_uint(x);
  return (u & 0x80000000u) ? ~u : (u | 0x80000000u);
}
__device__ __forceinline__ float dec_f32(unsigned e) {
  unsigned u = (e & 0x80000000u) ? (e & 0x7fffffffu) : ~e;
  return __uint_as_float(u);
}

__device__ __forceinline__ float fdot2f(int a, int b, float c) {
#if __has_builtin(__builtin_amdgcn_fdot2)
  return __builtin_amdgcn_fdot2(__builtin_bit_cast(h2f, a),
                                __builtin_bit_cast(h2f, b), c, false);
#else
  const __half2 ha = __builtin_bit_cast(__half2, a);
  const __half2 hb = __builtin_bit_cast(__half2, b);
  const float2 fa = __half22float2(ha), fb = __half22float2(hb);
  return fmaf(fa.y, fb.y, fmaf(fa.x, fb.x, c));
#endif
}

// ---------------- mm body (128 threads, 64 rows/block) ----------------
template <int K, int MODE>
__device__ __forceinline__ void mm_body(
    char* smemc, int bid, const float* __restrict__ in,
    const __half* __restrict__ hin, const __half* __restrict__ agg,
    const float* __restrict__ stats_in, const float* __restrict__ gamma,
    const float* __restrict__ beta, const float* __restrict__ W,
    const float* __restrict__ bias, __half* __restrict__ y16,
    float* __restrict__ stats_out) {
  constexpr int NPH = K / 64;
  __half2* Wl2 = (__half2*)smemc;
  __half2* AT2 = (__half2*)(smemc + (K / 2) * HH * 4);
  float* ssl = (float*)(smemc + (K / 2) * HH * 4 + 32 * 68 * 4);
  float* sred = ssl + 128;
  const int t = threadIdx.x;
  if (MODE != 0) {
    if (t < 64) {
      const float inv = 1.f / (float)NN;
      const float mean = stats_in[t] * inv;
      const float var = stats_in[64 + t] * inv - mean * mean;
      const float sc = gamma[t] * rsqrtf(var + BN_EPS);
      ssl[t] = sc;
      ssl[64 + t] = fmaf(-mean, sc, beta[t]);
    }
    __syncthreads();
  }
#pragma unroll
  for (int i = 0; i < K / 4; ++i) {
    const int idx = t + i * 128;
    const int kk = idx >> 6, c = idx & 63;
    Wl2[idx] = __floats2half2_rn(W[(2 * kk) * HH + c], W[(2 * kk + 1) * HH + c]);
  }
  const int srow = t >> 1, shalf = t & 1;
  const int grow_s = bid * 64 + srow;
  const int cg = t & 7, rg = t >> 3;
  const int c0 = cg * 8, r0 = rg * 4;
  float acc[4][8] = {};

#pragma unroll
  for (int p = 0; p < NPH; ++p) {
    if (p > 0) __syncthreads();
    if (grow_s < NN) {
      if (MODE == 0) {
#pragma unroll
        for (int q = 0; q < 4; ++q) {
          const int cc = p * 64 + shalf * 32 + q * 8;
          const float4 v0 = *(const float4*)&in[(size_t)grow_s * K + cc];
          const float4 v1 = *(const float4*)&in[(size_t)grow_s * K + cc + 4];
          const int kk = shalf * 16 + q * 4;
          AT2[(kk + 0) * 68 + srow] = __floats2half2_rn(v0.x, v0.y);
          AT2[(kk + 1) * 68 + srow] = __floats2half2_rn(v0.z, v0.w);
          AT2[(kk + 2) * 68 + srow] = __floats2half2_rn(v1.x, v1.y);
          AT2[(kk + 3) * 68 + srow] = __floats2half2_rn(v1.z, v1.w);
        }
      } else {
#pragma unroll
        for (int q = 0; q < 4; ++q) {
          const int cc = shalf * 32 + q * 8;
          const int4 rv = *(const int4*)&hin[grow_s * HH + cc];
          const __half2* hp = (const __half2*)&rv;
          float f[8];
          {
            const float2 f0 = __half22float2(hp[0]);
            const float2 f1 = __half22float2(hp[1]);
            const float2 f2 = __half22float2(hp[2]);
            const float2 f3 = __half22float2(hp[3]);
            f[0] = f0.x; f[1] = f0.y; f[2] = f1.x; f[3] = f1.y;
            f[4] = f2.x; f[5] = f2.y; f[6] = f3.x; f[7] = f3.y;
          }
#pragma unroll
          for (int j = 0; j < 8; ++j)
            f[j] = fmaxf(fmaf(f[j], ssl[cc + j], ssl[64 + cc + j]), 0.f);
          if (MODE == 2) {
            const int4 av = *(const int4*)&agg[grow_s * HH + cc];
            const __half2* ap = (const __half2*)&av;
            const float2 a0 = __half22float2(ap[0]);
            const float2 a1 = __half22float2(ap[1]);
            const float2 a2 = __half22float2(ap[2]);
            const float2 a3 = __half22float2(ap[3]);
            f[0] += a0.x; f[1] += a0.y; f[2] += a1.x; f[3] += a1.y;
            f[4] += a2.x; f[5] += a2.y; f[6] += a3.x; f[7] += a3.y;
          }
          const int kk = shalf * 16 + q * 4;
          AT2[(kk + 0) * 68 + srow] = __floats2half2_rn(f[0], f[1]);
          AT2[(kk + 1) * 68 + srow] = __floats2half2_rn(f[2], f[3]);
          AT2[(kk + 2) * 68 + srow] = __floats2half2_rn(f[4], f[5]);
          AT2[(kk + 3) * 68 + srow] = __floats2half2_rn(f[6], f[7]);
        }
      }
    } else {
      const __half2 z = __floats2half2_rn(0.f, 0.f);
#pragma unroll
      for (int i2 = 0; i2 < 16; ++i2) AT2[(shalf * 16 + i2) * 68 + srow] = z;
    }
    __syncthreads();
#pragma unroll 8
    for (int kk = 0; kk < 32; ++kk) {
      const int4 w0 = *(const int4*)&Wl2[(p * 32 + kk) * HH + c0];
      const int4 w1 = *(const int4*)&Wl2[(p * 32 + kk) * HH + c0 + 4];
      const int4 av = *(const int4*)&AT2[kk * 68 + r0];
      const int wu[8] = {w0.x, w0.y, w0.z, w0.w, w1.x, w1.y, w1.z, w1.w};
      const int au[4] = {av.x, av.y, av.z, av.w};
#pragma unroll
      for (int r = 0; r < 4; ++r)
#pragma unroll
        for (int c = 0; c < 8; ++c)
          acc[r][c] = fdot2f(au[r], wu[c], acc[r][c]);
    }
  }
  const float4 bb0 = *(const float4*)&bias[c0];
  const float4 bb1 = *(const float4*)&bias[c0 + 4];
  const float bbv[8] = {bb0.x, bb0.y, bb0.z, bb0.w, bb1.x, bb1.y, bb1.z, bb1.w};
  float st_s[8] = {}, st_q[8] = {};
  const int row0 = bid * 64 + r0;
#pragma unroll
  for (int ri = 0; ri < 4; ++ri) {
    const int grow = row0 + ri;
    if (grow < NN) {
      float o[8];
#pragma unroll
      for (int c = 0; c < 8; ++c) {
        o[c] = acc[ri][c] + bbv[c];
        st_s[c] += o[c];
        st_q[c] = fmaf(o[c], o[c], st_q[c]);
      }
      const __half2 p0 = __floats2half2_rn(o[0], o[1]);
      const __half2 p1 = __floats2half2_rn(o[2], o[3]);
      const __half2 p2 = __floats2half2_rn(o[4], o[5]);
      const __half2 p3 = __floats2half2_rn(o[6], o[7]);
      int4 pk;
      pk.x = *(const int*)&p0; pk.y = *(const int*)&p1;
      pk.z = *(const int*)&p2; pk.w = *(const int*)&p3;
      *(int4*)&y16[grow * HH + c0] = pk;
    }
  }
#pragma unroll
  for (int off = 8; off <= 32; off <<= 1) {
#pragma unroll
    for (int c = 0; c < 8; ++c) {
      st_s[c] += __shfl_xor(st_s[c], off);
      st_q[c] += __shfl_xor(st_q[c], off);
    }
  }
  const int wave = t >> 6, lane = t & 63;
  if (lane < 8) {
#pragma unroll
    for (int c = 0; c < 8; ++c) {
      sred[wave * 128 + lane * 8 + c] = st_s[c];
      sred[wave * 128 + 64 + lane * 8 + c] = st_q[c];
    }
  }
  __syncthreads();
  atomicAdd(&stats_out[t], sred[t] + sred[128 + t]);
}

// ---------------- CSR-build bodies ----------------
__device__ __forceinline__ void bcount_body(char* smemc, int bid,
                                            const int* __restrict__ ei,
                                            int* __restrict__ bcnt) {
  int* hist = (int*)smemc;
  const int t = threadIdx.x;
  hist[t] = 0; hist[t + 128] = 0;
  __syncthreads();
  for (int e = bid * 128 + t; e < EE; e += NB_BC * 128)
    atomicAdd(&hist[ei[EE + e] >> 8], 1);
  __syncthreads();
  const int v0 = hist[t], v1 = hist[t + 128];
  if (v0) atomicAdd(&bcnt[t], v0);
  if (v1) atomicAdd(&bcnt[t + 128], v1);
}

__global__ void bscan_kernel(const int* __restrict__ bcnt,
                             int* __restrict__ bbase, int* __restrict__ bcur) {
  __shared__ int s[256];
  const int t = threadIdx.x;
  const int v = (t < NBKT) ? bcnt[t] : 0;
  s[t] = v;
  __syncthreads();
  for (int off = 1; off < 256; off <<= 1) {
    const int u = (t >= off) ? s[t - off] : 0;
    __syncthreads();
    s[t] += u;
    __syncthreads();
  }
  const int excl = s[t] - v;
  if (t < NBKT) {
    bbase[t] = excl;
    bcur[t] = excl;
  }
  if (t == 255) bbase[NBKT] = s[255];  // == EE
}

__device__ __forceinline__ void bscatter_body(
    char* smemc, int bid, const int* __restrict__ ei, int* __restrict__ bcur,
    unsigned long long* __restrict__ ebuf) {
  int* lcnt = (int*)smemc;
  int* lbase = lcnt + 256;
  const int t = threadIdx.x;
  lcnt[t] = 0; lcnt[t + 128] = 0;
  __syncthreads();
  const int e0 = bid * SCAT_CHUNK;
  int mysrc[8], mydl[8], mybkt[8], myloc[8];
#pragma unroll
  for (int i = 0; i < 8; ++i) {
    const int e = e0 + i * 128 + t;
    if (e < EE) {
      const int dst = ei[EE + e];
      mybkt[i] = dst >> 8;
      mydl[i] = dst & 255;
      mysrc[i] = ei[e];
      myloc[i] = atomicAdd(&lcnt[mybkt[i]], 1);
    } else {
      mybkt[i] = -1;
    }
  }
  __syncthreads();
  if (lcnt[t]) lbase[t] = atomicAdd(&bcur[t], lcnt[t]);
  if (lcnt[t + 128]) lbase[t + 128] = atomicAdd(&bcur[t + 128], lcnt[t + 128]);
  __syncthreads();
#pragma unroll
  for (int i = 0; i < 8; ++i) {
    if (mybkt[i] >= 0) {
      const int pos = lbase[mybkt[i]] + myloc[i];
      ebuf[pos] = ((unsigned long long)(unsigned)mydl[i] << 32) |
                  (unsigned)mysrc[i];
    }
  }
}

__device__ __forceinline__ void bcsr_body(
    char* smemc, int b, const int* __restrict__ bbase,
    const unsigned long long* __restrict__ ebuf, int* __restrict__ offs,
    int* __restrict__ srcs) {
  int* ldeg = (int*)smemc;
  int* sscan = ldeg + 256;
  int* lcur = sscan + 256;
  const int t = threadIdx.x;
  const int e0 = bbase[b], e1 = bbase[b + 1];
  ldeg[t] = 0;
  __syncthreads();
  for (int e = e0 + t; e < e1; e += 256)
    atomicAdd(&ldeg[(int)(ebuf[e] >> 32)], 1);
  __syncthreads();
  const int v = ldeg[t];
  sscan[t] = v;
  __syncthreads();
  for (int off = 1; off < 256; off <<= 1) {
    const int u = (t >= off) ? sscan[t - off] : 0;
    __syncthreads();
    sscan[t] += u;
    __syncthreads();
  }
  const int excl = sscan[t] - v;
  const int node = b * 256 + t;
  if (node < NN) offs[node] = e0 + excl;
  if (b == NBKT - 1 && t == 0) offs[NN] = EE;
  lcur[t] = e0 + excl;
  __syncthreads();
  for (int e = e0 + t; e < e1; e += 256) {
    const unsigned long long u = ebuf[e];
    const int dl = (int)(u >> 32);
    const int pos = atomicAdd(&lcur[dl], 1);
    srcs[pos] = (int)(u & 0xffffffffu);
  }
}

// gather (256 threads): agg16[n] = sum_{src} relu(BN(y[src]))
// explicit dual accumulators to break the load-latency chain
__device__ __forceinline__ void gather_body(
    char* smemc, int bid, const int* __restrict__ offs,
    const int* __restrict__ srcs, const __half* __restrict__ y,
    const float* __restrict__ stats_in, const float* __restrict__ gamma,
    const float* __restrict__ beta, __half* __restrict__ agg) {
  float* ssl = (float*)smemc;
  const int t = threadIdx.x;
  if (t < 64) {
    const float inv = 1.f / (float)NN;
    const float mean = stats_in[t] * inv;
    const float var = stats_in[64 + t] * inv - mean * mean;
    const float sc = gamma[t] * rsqrtf(var + BN_EPS);
    ssl[t] = sc;
    ssl[64 + t] = fmaf(-mean, sc, beta[t]);
  }
  __syncthreads();
  const int gid = bid * 256 + t;
  const int n = gid >> 3, lane = gid & 7;
  if (n >= NN) return;
  const int c0 = lane * 8;
  float sc[8], sh[8];
#pragma unroll
  for (int j = 0; j < 8; ++j) {
    sc[j] = ssl[c0 + j];
    sh[j] = ssl[64 + c0 + j];
  }
  const int s0 = offs[n], s1 = offs[n + 1];
  float a[8] = {}, b[8] = {};
  int j = s0;
  for (; j + 1 < s1; j += 2) {
    const int4 rvA = *(const int4*)&y[srcs[j] * HH + c0];
    const int4 rvB = *(const int4*)&y[srcs[j + 1] * HH + c0];
    const __half2* hA = (const __half2*)&rvA;
    const __half2* hB = (const __half2*)&rvB;
    const float2 fA0 = __half22float2(hA[0]);
    const float2 fA1 = __half22float2(hA[1]);
    const float2 fA2 = __half22float2(hA[2]);
    const float2 fA3 = __half22float2(hA[3]);
    const float2 fB0 = __half22float2(hB[0]);
    const float2 fB1 = __half22float2(hB[1]);
    const float2 fB2 = __half22float2(hB[2]);
    const float2 fB3 = __half22float2(hB[3]);
    a[0] += fmaxf(fmaf(fA0.x, sc[0], sh[0]), 0.f);
    a[1] += fmaxf(fmaf(fA0.y, sc[1], sh[1]), 0.f);
    a[2] += fmaxf(fmaf(fA1.x, sc[2], sh[2]), 0.f);
    a[3] += fmaxf(fmaf(fA1.y, sc[3], sh[3]), 0.f);
    a[4] += fmaxf(fmaf(fA2.x, sc[4], sh[4]), 0.f);
    a[5] += fmaxf(fmaf(fA2.y, sc[5], sh[5]), 0.f);
    a[6] += fmaxf(fmaf(fA3.x, sc[6], sh[6]), 0.f);
    a[7] += fmaxf(fmaf(fA3.y, sc[7], sh[7]), 0.f);
    b[0] += fmaxf(fmaf(fB0.x, sc[0], sh[0]), 0.f);
    b[1] += fmaxf(fmaf(fB0.y, sc[1], sh[1]), 0.f);
    b[2] += fmaxf(fmaf(fB1.x, sc[2], sh[2]), 0.f);
    b[3] += fmaxf(fmaf(fB1.y, sc[3], sh[3]), 0.f);
    b[4] += fmaxf(fmaf(fB2.x, sc[4], sh[4]), 0.f);
    b[5] += fmaxf(fmaf(fB2.y, sc[5], sh[5]), 0.f);
    b[6] += fmaxf(fmaf(fB3.x, sc[6], sh[6]), 0.f);
    b[7] += fmaxf(fmaf(fB3.y, sc[7], sh[7]), 0.f);
  }
  if (j < s1) {
    const int4 rv = *(const int4*)&y[srcs[j] * HH + c0];
    const __half2* hp = (const __half2*)&rv;
    const float2 f0 = __half22float2(hp[0]);
    const float2 f1 = __half22float2(hp[1]);
    const float2 f2 = __half22float2(hp[2]);
    const float2 f3 = __half22float2(hp[3]);
    a[0] += fmaxf(fmaf(f0.x, sc[0], sh[0]), 0.f);
    a[1] += fmaxf(fmaf(f0.y, sc[1], sh[1]), 0.f);
    a[2] += fmaxf(fmaf(f1.x, sc[2], sh[2]), 0.f);
    a[3] += fmaxf(fmaf(f1.y, sc[3], sh[3]), 0.f);
    a[4] += fmaxf(fmaf(f2.x, sc[4], sh[4]), 0.f);
    a[5] += fmaxf(fmaf(f2.y, sc[5], sh[5]), 0.f);
    a[6] += fmaxf(fmaf(f3.x, sc[6], sh[6]), 0.f);
    a[7] += fmaxf(fmaf(f3.y, sc[7], sh[7]), 0.f);
  }
#pragma unroll
  for (int i = 0; i < 8; ++i) a[i] += b[i];
  const __half2 p0 = __floats2half2_rn(a[0], a[1]);
  const __half2 p1 = __floats2half2_rn(a[2], a[3]);
  const __half2 p2 = __floats2half2_rn(a[4], a[5]);
  const __half2 p3 = __floats2half2_rn(a[6], a[7]);
  int4 pk;
  pk.x = *(const int*)&p0; pk.y = *(const int*)&p1;
  pk.z = *(const int*)&p2; pk.w = *(const int*)&p3;
  *(int4*)&agg[n * HH + c0] = pk;
}

// readout (256 threads)
template <int WMODE>
__device__ __forceinline__ void readout_body(
    char* smemc, int bid, const __half* __restrict__ y2,
    const float* __restrict__ stats_in, const float* __restrict__ gamma,
    const float* __restrict__ beta, float* __restrict__ hout,
    const float* __restrict__ linW, const float* __restrict__ linb,
    const int* __restrict__ batch, unsigned* __restrict__ outmax) {
  float* Wl = (float*)smemc;                 // 576
  float* lb = Wl + 576;                      // 8
  float* ssl = lb + 8;                       // 128
  unsigned* smax = (unsigned*)(ssl + 128);   // 64
  const int t = threadIdx.x;
  if (t < 64) {
#pragma unroll
    for (int j = 0; j < 8; ++j) Wl[t * 9 + j] = linW[t * 8 + j];
    const float inv = 1.f / (float)NN;
    const float mean = stats_in[t] * inv;
    const float var = stats_in[64 + t] * inv - mean * mean;
    const float sc = gamma[t] * rsqrtf(var + BN_EPS);
    ssl[t] = sc;
    ssl[64 + t] = fmaf(-mean, sc, beta[t]);
  }
  if (t < 8) lb[t] = linb[t];
  if (t >= 64 && t < 128) smax[t - 64] = 0u;
  const int gfirst = batch[bid * RNODES < NN ? bid * RNODES : NN - 1];
  __syncthreads();
  const int nl = t >> 3;
  const int c0 = (t & 7) * 8;
  const int b0 = t & 1, b1 = (t >> 1) & 1, b2 = (t >> 2) & 1;
#pragma unroll
  for (int chunk = 0; chunk < RNODES / 32; ++chunk) {
    const int n = bid * RNODES + chunk * 32 + nl;
    if (n < NN) {
      float hv[8];
      {
        const int4 rv = *(const int4*)&y2[n * HH + c0];
        const __half2* hp = (const __half2*)&rv;
        const float2 f0 = __half22float2(hp[0]);
        const float2 f1 = __half22float2(hp[1]);
        const float2 f2 = __half22float2(hp[2]);
        const float2 f3 = __half22float2(hp[3]);
        hv[0] = fmaxf(fmaf(f0.x, ssl[c0 + 0], ssl[64 + c0 + 0]), 0.f);
        hv[1] = fmaxf(fmaf(f0.y, ssl[c0 + 1], ssl[64 + c0 + 1]), 0.f);
        hv[2] = fmaxf(fmaf(f1.x, ssl[c0 + 2], ssl[64 + c0 + 2]), 0.f);
        hv[3] = fmaxf(fmaf(f1.y, ssl[c0 + 3], ssl[64 + c0 + 3]), 0.f);
        hv[4] = fmaxf(fmaf(f2.x, ssl[c0 + 4], ssl[64 + c0 + 4]), 0.f);
        hv[5] = fmaxf(fmaf(f2.y, ssl[c0 + 5], ssl[64 + c0 + 5]), 0.f);
        hv[6] = fmaxf(fmaf(f3.x, ssl[c0 + 6], ssl[64 + c0 + 6]), 0.f);
        hv[7] = fmaxf(fmaf(f3.y, ssl[c0 + 7], ssl[64 + c0 + 7]), 0.f);
      }
      if (WMODE == 1) {
        *(float4*)&hout[n * HH + c0] = make_float4(hv[0], hv[1], hv[2], hv[3]);
        *(float4*)&hout[n * HH + c0 + 4] =
            make_float4(hv[4], hv[5], hv[6], hv[7]);
      }
      float rr[8] = {0, 0, 0, 0, 0, 0, 0, 0};
#pragma unroll
      for (int j = 0; j < 8; ++j) {
        const float a = hv[j];
        const int k = c0 + j;
#pragma unroll
        for (int u = 0; u < 8; ++u) rr[u] = fmaf(a, Wl[k * 9 + u], rr[u]);
      }
      float s4[4];
#pragma unroll
      for (int i = 0; i < 4; ++i) {
        const float keepv = b0 ? rr[2 * i + 1] : rr[2 * i];
        const float send = b0 ? rr[2 * i] : rr[2 * i + 1];
        s4[i] = keepv + __shfl_xor(send, 1);
      }
      float s2[2];
#pragma unroll
      for (int i = 0; i < 2; ++i) {
        const float keepv = b1 ? s4[2 * i + 1] : s4[2 * i];
        const float send = b1 ? s4[2 * i] : s4[2 * i + 1];
        s2[i] = keepv + __shfl_xor(send, 2);
      }
      const float keepv = b2 ? s2[1] : s2[0];
      const float send = b2 ? s2[0] : s2[1];
      const float v = keepv + __shfl_xor(send, 4) + lb[t & 7];
      const int g = batch[n];
      const int gidx = g - gfirst;
      const unsigned ev = enc_f32(v);
      if (gidx < 8)
        atomicMax(&smax[gidx * 8 + (t & 7)], ev);
      else
        atomicMax(&outmax[g * 8 + (t & 7)], ev);
    }
  }
  __syncthreads();
  if (t < 64) {
    const unsigned vv = smax[t];
    if (vv) atomicMax(&outmax[(gfirst + (t >> 3)) * 8 + (t & 7)], vv);
  }
}

// ---------------- fused kernels (independent block ranges only) ----------------
template <int K, int MODE, int TAIL>
__global__ __launch_bounds__(128) void mm_fused_kernel(
    const float* in, const __half* hin, const __half* agg,
    const float* stats_in, const float* gamma, const float* beta,
    const float* W, const float* bias, __half* y16, float* stats_out,
    const int* ei, int* bcnt, int* bcur, unsigned long long* ebuf) {
  constexpr int SMEM = (K / 2) * HH * 4 + 32 * 68 * 4 + 512 + 1024;
  __shared__ alignas(16) char smem[SMEM];
  const int bid = blockIdx.x;
  if (bid < NBLK) {
    mm_body<K, MODE>(smem, bid, in, hin, agg, stats_in, gamma, beta, W, bias,
                     y16, stats_out);
  } else if (TAIL == 1) {
    bcount_body(smem, bid - NBLK, ei, bcnt);
  } else if (TAIL == 2) {
    bscatter_body(smem, bid - NBLK, ei, bcur, ebuf);
  }
}

template <int WMODE, int TAIL>
__global__ __launch_bounds__(256) void readout_fused_kernel(
    const __half* y2, const float* stats_in, const float* gamma,
    const float* beta, float* hout, const float* linW, const float* linb,
    const int* batch, unsigned* outmax, const int* offs_in,
    const int* srcs_in, __half* agg, const int* bbase,
    const unsigned long long* ebuf, int* offs_out, int* srcs_out) {
  __shared__ alignas(16) char smem[3136];
  const int bid = blockIdx.x;
  if (bid < NRD) {
    readout_body<WMODE>(smem, bid, y2, stats_in, gamma, beta, hout, linW,
                        linb, batch, outmax);
  } else if (TAIL == 1) {
    bcsr_body(smem, bid - NRD, bbase, ebuf, offs_out, srcs_out);
  } else if (TAIL == 2) {
    gather_body(smem, bid - NRD, offs_in, srcs_in, y2, stats_in, gamma, beta,
                agg);
  }
}

__global__ __launch_bounds__(256) void gather_kernel(
    const int* offs, const int* srcs, const __half* y, const float* stats_in,
    const float* gamma, const float* beta, __half* agg) {
  __shared__ alignas(16) char smem[512];
  gather_body(smem, blockIdx.x, offs, srcs, y, stats_in, gamma, beta, agg);
}

__global__ void combine_kernel(const unsigned* __restrict__ outmax,
                               float* __restrict__ out) {
  const int i = blockIdx.x * 64 + threadIdx.x;  // 8 x 64 = 512
  float s = 0.f;
#pragma unroll
  for (int l = 0; l < 4; ++l) s += dec_f32(outmax[l * GG * TT + i]);
  out[i] = s;
}

extern "C" void kernel_launch(void* const* d_in, const int* in_sizes, int n_in,
                              void* d_out, int out_size, void* d_ws,
                              size_t ws_size, hipStream_t stream) {
  const float* x      = (const float*)d_in[0];
  const int*   ei     = (const int*)d_in[1];
  const int*   batch  = (const int*)d_in[2];
  const float* fh_W1  = (const float*)d_in[3];
  const float* fh_b1  = (const float*)d_in[4];
  const float* fh_g1  = (const float*)d_in[5];
  const float* fh_be1 = (const float*)d_in[6];
  const float* fh_W2  = (const float*)d_in[7];
  const float* fh_b2  = (const float*)d_in[8];
  const float* fh_g2  = (const float*)d_in[9];
  const float* fh_be2 = (const float*)d_in[10];
  const float* cv_W1  = (const float*)d_in[11];
  const float* cv_b1  = (const float*)d_in[12];
  const float* cv_g1  = (const float*)d_in[13];
  const float* cv_be1 = (const float*)d_in[14];
  const float* cv_W2  = (const float*)d_in[15];
  const float* cv_b2  = (const float*)d_in[16];
  const float* cv_g2  = (const float*)d_in[17];
  const float* cv_be2 = (const float*)d_in[18];
  const float* lin_W  = (const float*)d_in[19];
  const float* lin_b  = (const float*)d_in[20];

  float* out = (float*)d_out;  // [64,8]
  float* h = out + GG * TT;    // [N,64] fp32 final h

  char* w = (char*)d_ws;
  float* stats = (float*)w;                       w += 8 * 128 * 4;   // 8 slots
  unsigned* outmax = (unsigned*)w;                w += 4 * GG * TT * 4;
  int* bcnt = (int*)w;                            w += 256 * 4;
  int* bbase = (int*)w;                           w += 256 * 4;
  int* bcur = (int*)w;                            w += 256 * 4;
  int* offs = (int*)w;                            w += (NN + 1) * 4;
  int* srcs = (int*)w;                            w += (size_t)EE * 4;
  w = (char*)(((size_t)w + 15) & ~(size_t)15);
  __half* y1 = (__half*)w;                        w += (size_t)NN * HH * 2;
  __half* y2 = (__half*)w;                        w += (size_t)NN * HH * 2;
  w = (char*)(((size_t)w + 15) & ~(size_t)15);
  __half* agg = (__half*)w;                       w += (size_t)NN * HH * 2;
  unsigned long long* ebuf = (unsigned long long*)agg;  // dead before gather

  // stats(4KB)+outmax(8KB)+bcnt(1KB) contiguous: one memset
  hipMemsetAsync(stats, 0, (8 * 128 + 4 * GG * TT + 256) * sizeof(float),
                 stream);

  // K1: first_h mm1  ||  bucket count
  mm_fused_kernel<FIN, 0, 1><<<NBLK + NB_BC, 128, 0, stream>>>(
      x, nullptr, nullptr, nullptr, nullptr, nullptr, fh_W1, fh_b1, y1, stats,
      ei, bcnt, bcur, ebuf);
  // bucket scan (tiny)
  bscan_kernel<<<1, 256, 0, stream>>>(bcnt, bbase, bcur);
  // K2: first_h mm2  ||  bucket scatter
  mm_fused_kernel<HH, 1, 2><<<NBLK + NSC, 128, 0, stream>>>(
      nullptr, y1, nullptr, stats, fh_g1, fh_be1, fh_W2, fh_b2, y2,
      stats + 128, ei, bcnt, bcur, ebuf);
  // K3: readout layer-0  ||  per-bucket CSR finalize
  readout_fused_kernel<0, 1><<<NRD + NBKT, 256, 0, stream>>>(
      y2, stats + 128, fh_g2, fh_be2, h, lin_W, lin_b, batch, outmax,
      nullptr, nullptr, nullptr, bbase, ebuf, offs, srcs);
  // K4: gather for conv layer 0
  gather_kernel<<<NGA, 256, 0, stream>>>(offs, srcs, y2, stats + 128, fh_g2,
                                         fh_be2, agg);

  for (int l = 0; l < NCONVS; ++l) {
    float* sprev = stats + (1 + 2 * l) * 128;
    float* sA = stats + (2 + 2 * l) * 128;
    float* sB = stats + (3 + 2 * l) * 128;
    const float* pg = (l == 0) ? fh_g2 : cv_g2 + (l - 1) * HH;
    const float* pb = (l == 0) ? fh_be2 : cv_be2 + (l - 1) * HH;
    mm_fused_kernel<HH, 2, 0><<<NBLK, 128, 0, stream>>>(
        nullptr, y2, agg, sprev, pg, pb, cv_W1 + l * HH * HH, cv_b1 + l * HH,
        y1, sA, ei, bcnt, bcur, ebuf);
    mm_fused_kernel<HH, 1, 0><<<NBLK, 128, 0, stream>>>(
        nullptr, y1, nullptr, sA, cv_g1 + l * HH, cv_be1 + l * HH,
        cv_W2 + l * HH * HH, cv_b2 + l * HH, y2, sB, ei, bcnt, bcur, ebuf);
    if (l < NCONVS - 1) {
      readout_fused_kernel<0, 2><<<NRD + NGA, 256, 0, stream>>>(
          y2, sB, cv_g2 + l * HH, cv_be2 + l * HH, h,
          lin_W + (l + 1) * HH * TT, lin_b + (l + 1) * TT, batch,
          outmax + (l + 1) * GG * TT, offs, srcs, agg, nullptr, nullptr,
          nullptr, nullptr);
    } else {
      readout_fused_kernel<1, 0><<<NRD, 256, 0, stream>>>(
          y2, sB, cv_g2 + l * HH, cv_be2 + l * HH, h,
          lin_W + (l + 1) * HH * TT, lin_b + (l + 1) * TT, batch,
          outmax + (l + 1) * GG * TT, nullptr, nullptr, nullptr, nullptr,
          nullptr, nullptr, nullptr);
    }
  }
  combine_kernel<<<8, 64, 0, stream>>>(outmax, out);
}